// Round 9
// baseline (154.290 us; speedup 1.0000x reference)
//
#include <hip/hip_runtime.h>

#define N_ROWS 16384
#define K_CB   8192
#define D_DIM  64
#define NSPLIT 8
#define SPLIT_K (K_CB / NSPLIT)          // 1024
#define STAGE  32                        // codebook rows per LDS stage (one 32-n tile)
#define NSTAGES (SPLIT_K / STAGE)        // 32
#define NXGRP  (N_ROWS / 128)            // 128 row-groups

typedef unsigned short u16;
typedef unsigned int   u32;
typedef unsigned long long u64;
typedef __attribute__((ext_vector_type(8)))  short short8v;  // 8 bf16 (4 VGPRs)
typedef __attribute__((ext_vector_type(16))) float f32x16;   // 32x32 MFMA C/D

static __device__ __forceinline__ u16 f2bf(float f) {        // RNE fp32->bf16
    unsigned u = __float_as_uint(f);
    return (u16)((u + 0x7FFFu + ((u >> 16) & 1u)) >> 16);
}
static __device__ __forceinline__ float bf2f(u16 h) {
    return __uint_as_float(((unsigned)h) << 16);
}

// ---- kernel 0: codebook prep (hi/lo split + 0.5||c||^2) + zero done[] ----
__global__ void vq_prep_kernel(const float* __restrict__ cb,
                               u16* __restrict__ cb_hi, u16* __restrict__ cb_lo,
                               float* __restrict__ hcsq, int* __restrict__ done)
{
    const int wave = threadIdx.x >> 6;
    const int lane = threadIdx.x & 63;
    if (threadIdx.x == 0 && blockIdx.x < NXGRP) done[blockIdx.x] = 0;
#pragma unroll
    for (int rr = 0; rr < 2; ++rr) {
        const int r = blockIdx.x * 8 + wave * 2 + rr;
        const float v = cb[r * D_DIM + lane];
        const u16 h = f2bf(v);
        cb_hi[r * D_DIM + lane] = h;
        cb_lo[r * D_DIM + lane] = f2bf(v - bf2f(h));
        float d = v * v;
#pragma unroll
        for (int m = 1; m < 64; m <<= 1) d += __shfl_xor(d, m, 64);
        if (lane == 0) hcsq[r] = 0.5f * d;
    }
}

// ---- kernel 1: 32x32x16 MFMA scores + float-key argmax + exact rescore +
//      last-block-per-rowgroup gather (no separate gather kernel) ----
// score(m,n) = dot(x_m, c_n) - 0.5||c_n||^2 ; argmin dist == argmax score.
// A operand: m=lane&31, k=(lane>>5)*8+j. B operand: n=lane&31, k=(lane>>5)*8+j.
// C/D: col(n)=lane&31, row(m)=(reg&3)+8*(reg>>2)+4*(lane>>5)   [m74/m101].
// Key trick: key = float_bits(score) & ~31 | stage; v_max_f32 keeps best
// (<=31 ulp perturbation -> absorbed by exact rescore); bits&31 recovers stage.
__global__ __launch_bounds__(256, 4) void vq_mfma_kernel(
    const float* __restrict__ enc, const float* __restrict__ cb,
    const u16* __restrict__ cb_hi, const u16* __restrict__ cb_lo,
    const float* __restrict__ hcsq, u64* __restrict__ winner,
    int* __restrict__ done, float* __restrict__ out)
{
    // carve: ldsb 2 bufs x 8KB (4096 u32) | hcsq 4KB = 20.5 KB.
    // post-loop: keys[128][33] reuses the front (ldsb dead by then).
    __shared__ __align__(16) u32 smem[4096 + 1024];
    u16*   ldsb  = (u16*)smem;
    float* lds_h = (float*)(smem + 4096);
    u32*   keys  = smem;
    __shared__ int s_old;

    const int tid  = threadIdx.x;
    const int wave = tid >> 6;
    const int lane = tid & 63;
    const int n32  = lane & 31;
    const int lh   = lane >> 5;
    const int B0   = blockIdx.y * SPLIT_K;
    const int rowbase = blockIdx.x * 128 + wave * 32;      // 32 m-rows per wave

    // ---- A fragments (hi/lo per k-chunk), converted in-register once ----
    short8v a_hi[4], a_lo[4];
    const float* arow = enc + (size_t)(rowbase + n32) * D_DIM + lh * 8;
#pragma unroll
    for (int c = 0; c < 4; ++c) {
        const float4 u0 = ((const float4*)(arow + c * 16))[0];
        const float4 u1 = ((const float4*)(arow + c * 16))[1];
        const float vv[8] = {u0.x,u0.y,u0.z,u0.w,u1.x,u1.y,u1.z,u1.w};
        short8v h8, l8;
#pragma unroll
        for (int j = 0; j < 8; ++j) {
            const u16 h = f2bf(vv[j]);
            h8[j] = (short)h;
            l8[j] = (short)f2bf(vv[j] - bf2f(h));
        }
        a_hi[c] = h8; a_lo[c] = l8;
    }

    // ---- split's hcsq into LDS (once) ----
#pragma unroll
    for (int i = 0; i < SPLIT_K / 256; ++i)
        lds_h[tid + i * 256] = hcsq[B0 + tid + i * 256];

    // ---- DMA mapping: wave (half = w>>1) issues c = (w&1)*2 + {0,1} ----
    const int half  = wave >> 1;
    const int cpair = (wave & 1) * 2;
    const u16* gbase = (half ? cb_lo : cb_hi) + (size_t)B0 * D_DIM;

#define DMA_STAGE(buf_, s_)                                                        \
    do {                                                                           \
        _Pragma("unroll")                                                          \
        for (int i_ = 0; i_ < 2; ++i_) {                                           \
            const int c_ = cpair + i_;                                             \
            __builtin_amdgcn_global_load_lds(                                      \
                (const __attribute__((address_space(1))) void*)                    \
                    (gbase + ((size_t)(s_) * STAGE + n32) * D_DIM + (2*c_+lh)*8),  \
                (__attribute__((address_space(3))) void*)                          \
                    (ldsb + (buf_) * 4096 + half * 2048 + c_ * 512),               \
                16, 0, 0);                                                         \
        }                                                                          \
    } while (0)

    DMA_STAGE(0, 0);
    __syncthreads();                                       // stage 0 resident

    f32x16 z;
#pragma unroll
    for (int r = 0; r < 16; ++r) z[r] = 0.f;               // never written: chain seed

    float bkey[16];
#pragma unroll
    for (int r = 0; r < 16; ++r) bkey[r] = -INFINITY;

    for (int s = 0; s < NSTAGES; ++s) {
        const int buf = s & 1;
        DMA_STAGE(buf ^ 1, (s + 1) & (NSTAGES - 1));       // async prefetch (wrap ok)

        const u16* bb = ldsb + buf * 4096;
        short8v bh[4], bl[4];
#pragma unroll
        for (int c = 0; c < 4; ++c) {
            bh[c] = *(const short8v*)(bb + c * 512 + lane * 8);
            bl[c] = *(const short8v*)(bb + 2048 + c * 512 + lane * 8);
        }
        const float h = lds_h[s * STAGE + n32];

        // single 12-deep chain: hi.hi x4, hi.lo x4, lo.hi x4 (lo.lo ~2^-18: dropped)
        f32x16 acc;
        acc = __builtin_amdgcn_mfma_f32_32x32x16_bf16(a_hi[0], bh[0], z,   0,0,0);
        acc = __builtin_amdgcn_mfma_f32_32x32x16_bf16(a_hi[1], bh[1], acc, 0,0,0);
        acc = __builtin_amdgcn_mfma_f32_32x32x16_bf16(a_hi[2], bh[2], acc, 0,0,0);
        acc = __builtin_amdgcn_mfma_f32_32x32x16_bf16(a_hi[3], bh[3], acc, 0,0,0);
        acc = __builtin_amdgcn_mfma_f32_32x32x16_bf16(a_hi[0], bl[0], acc, 0,0,0);
        acc = __builtin_amdgcn_mfma_f32_32x32x16_bf16(a_hi[1], bl[1], acc, 0,0,0);
        acc = __builtin_amdgcn_mfma_f32_32x32x16_bf16(a_hi[2], bl[2], acc, 0,0,0);
        acc = __builtin_amdgcn_mfma_f32_32x32x16_bf16(a_hi[3], bl[3], acc, 0,0,0);
        acc = __builtin_amdgcn_mfma_f32_32x32x16_bf16(a_lo[0], bh[0], acc, 0,0,0);
        acc = __builtin_amdgcn_mfma_f32_32x32x16_bf16(a_lo[1], bh[1], acc, 0,0,0);
        acc = __builtin_amdgcn_mfma_f32_32x32x16_bf16(a_lo[2], bh[2], acc, 0,0,0);
        acc = __builtin_amdgcn_mfma_f32_32x32x16_bf16(a_lo[3], bh[3], acc, 0,0,0);

        // float-packed key argmax: 4 VALU per element (sub, and, or, max)
#pragma unroll
        for (int r = 0; r < 16; ++r) {
            const float sc = acc[r] - h;
            const u32 kb = (__float_as_uint(sc) & 0xFFFFFFE0u) | (u32)s;
            bkey[r] = fmaxf(bkey[r], __uint_as_float(kb));
        }
        __syncthreads();   // all waves done reading buf; prefetch drained (vmcnt0)
    }
#undef DMA_STAGE

    // ---- per-class winners -> keys[row][cls] in LDS (reuses ldsb region) ----
#pragma unroll
    for (int r = 0; r < 16; ++r) {
        const int m = (r & 3) + 8 * (r >> 2) + 4 * lh;
        keys[(wave * 32 + m) * 33 + n32] = __float_as_uint(bkey[r]);
    }
    __syncthreads();

    // ---- top-2 of 32 classes per row (2 threads/row), exact fp32 rescore ----
    {
        const int lrow  = tid >> 1;
        const int hpart = tid & 1;
        float k1 = -INFINITY, k2 = -INFINITY; int c1i = 0, c2i = 0;
#pragma unroll
        for (int c = 0; c < 16; ++c) {
            const int cls = hpart * 16 + c;
            const float kf = __uint_as_float(keys[lrow * 33 + cls]);
            if (kf > k1)      { k2 = k1; c2i = c1i; k1 = kf; c1i = cls; }
            else if (kf > k2) { k2 = kf; c2i = cls; }
        }
        const float ok1 = __shfl_xor(k1, 1, 64);
        const float ok2 = __shfl_xor(k2, 1, 64);
        const int   oc1 = __shfl_xor(c1i, 1, 64);
        const int   oc2 = __shfl_xor(c2i, 1, 64);
        float m1, m2; int mi1, mi2;
        if (ok1 > k1) { m1 = ok1; mi1 = oc1;
                        m2 = (k1 > ok2) ? k1 : ok2; mi2 = (k1 > ok2) ? c1i : oc2; }
        else          { m1 = k1;  mi1 = c1i;
                        m2 = (ok1 > k2) ? ok1 : k2; mi2 = (ok1 > k2) ? oc1 : c2i; }

        const float ck   = hpart ? m2 : m1;
        const int   ccls = hpart ? mi2 : mi1;
        const int   cidx = B0 + (int)(__float_as_uint(ck) & 31u) * STAGE + ccls;
        const int   grow = blockIdx.x * 128 + lrow;

        const float4* cp = (const float4*)(cb  + (size_t)cidx * D_DIM);
        const float4* xp = (const float4*)(enc + (size_t)grow * D_DIM);
        float d = 0.f;
#pragma unroll
        for (int i = 0; i < 16; ++i) {
            const float4 cv = cp[i], xv = xp[i];
            float t;
            t = xv.x - cv.x; d = fmaf(t, t, d);
            t = xv.y - cv.y; d = fmaf(t, t, d);
            t = xv.z - cv.z; d = fmaf(t, t, d);
            t = xv.w - cv.w; d = fmaf(t, t, d);
        }
        // (distbits, idx) packed: u64 min == (min dist, then min idx) = jnp first-min.
        // 0xAAAA... ws poison exceeds any packed value (dist sign bit 0): free sentinel.
        const u64 packed = ((u64)__float_as_uint(d) << 32) | (u32)cidx;
        atomicMin(winner + grow, packed);
    }

    // ---- last-block-per-rowgroup gather ----
    __syncthreads();
    if (tid == 0) {
        __threadfence();                                   // release our atomicMins
        s_old = atomicAdd(done + blockIdx.x, 1);
    }
    __syncthreads();
    if (s_old == NSPLIT - 1) {
        __threadfence();                                   // acquire others' atomicMins
        const int rb = blockIdx.x * 128;
#pragma unroll
        for (int i = 0; i < 8; ++i) {
            const int g   = i * 256 + tid;                 // quad index 0..2047
            const int row = rb + (g >> 4);
            u64 w = 0;
            if ((lane & 15) == 0)                          // one coherent read per row
                w = atomicAdd(winner + row, 0ull);
            int idx = (int)(w & 0xFFFFFFFFu);
            idx = __shfl(idx, lane & 48, 64);              // broadcast within 16-lane group
            ((float4*)(out + (size_t)row * D_DIM))[g & 15] =
                ((const float4*)(cb + (size_t)idx * D_DIM))[g & 15];
        }
    }
}

extern "C" void kernel_launch(void* const* d_in, const int* in_sizes, int n_in,
                              void* d_out, int out_size, void* d_ws, size_t ws_size,
                              hipStream_t stream) {
    const float* enc = (const float*)d_in[0];   // 16384 x 64 fp32
    const float* cb  = (const float*)d_in[1];   // 8192 x 64 fp32
    float* out = (float*)d_out;

    // ws layout (~2.16 MB): cb_hi | cb_lo | hcsq | winner | done
    u16* cb_hi  = (u16*)d_ws;                       // 1 MB
    u16* cb_lo  = cb_hi + K_CB * D_DIM;             // 1 MB
    float* hcsq = (float*)(cb_lo + K_CB * D_DIM);   // 32 KB
    u64* winner = (u64*)(hcsq + K_CB);              // 128 KB (8-byte aligned)
    int* done   = (int*)(winner + N_ROWS);          // 512 B

    vq_prep_kernel<<<K_CB / 8, 256, 0, stream>>>(cb, cb_hi, cb_lo, hcsq, done);

    dim3 g1(NXGRP, NSPLIT);                         // 128 x 8 = 1024 blocks
    vq_mfma_kernel<<<g1, 256, 0, stream>>>(enc, cb, cb_hi, cb_lo, hcsq,
                                           winner, done, out);
}

// Round 10
// 125.165 us; speedup vs baseline: 1.2327x; 1.2327x over previous
//
#include <hip/hip_runtime.h>

#define N_ROWS 16384
#define K_CB   8192
#define D_DIM  64
#define NSPLIT 8
#define SPLIT_K (K_CB / NSPLIT)          // 1024
#define STAGE  64                        // codebook rows per LDS stage (two 32-n tiles)
#define NSTAGES (SPLIT_K / STAGE)        // 16  -> slot = 2*s+u in [0,32): 5 bits

typedef unsigned short u16;
typedef unsigned int   u32;
typedef unsigned long long u64;
typedef __attribute__((ext_vector_type(8)))  short short8v;  // 8 bf16 (4 VGPRs)
typedef __attribute__((ext_vector_type(16))) float f32x16;   // 32x32 MFMA C/D

static __device__ __forceinline__ u16 f2bf(float f) {        // RNE fp32->bf16
    unsigned u = __float_as_uint(f);
    return (u16)((u + 0x7FFFu + ((u >> 16) & 1u)) >> 16);
}
static __device__ __forceinline__ float bf2f(u16 h) {
    return __uint_as_float(((unsigned)h) << 16);
}

// ---- kernel 0: codebook prep. hi/lo split + 0.5*||c||^2. 8 rows/block. ----
__global__ void vq_prep_kernel(const float* __restrict__ cb,
                               u16* __restrict__ cb_hi, u16* __restrict__ cb_lo,
                               float* __restrict__ hcsq)
{
    const int wave = threadIdx.x >> 6;
    const int lane = threadIdx.x & 63;
#pragma unroll
    for (int rr = 0; rr < 2; ++rr) {
        const int r = blockIdx.x * 8 + wave * 2 + rr;
        const float v = cb[r * D_DIM + lane];
        const u16 h = f2bf(v);
        cb_hi[r * D_DIM + lane] = h;
        cb_lo[r * D_DIM + lane] = f2bf(v - bf2f(h));
        float d = v * v;
#pragma unroll
        for (int m = 1; m < 64; m <<= 1) d += __shfl_xor(d, m, 64);
        if (lane == 0) hcsq[r] = 0.5f * d;
    }
}

// ---- kernel 1: 32x32x16 MFMA scores + float-key argmax + exact rescore ----
// score(m,n) = dot(x_m, c_n) - 0.5||c_n||^2 ; argmin dist == argmax score.
// A operand: m=lane&31, k=(lane>>5)*8+j. B operand: n=lane&31, k=(lane>>5)*8+j.
// C/D: col(n)=lane&31, row(m)=(reg&3)+8*(reg>>2)+4*(lane>>5)   [m74/m101].
// Key: bits(score) & ~31 | slot, kept with v_max_f32 (<=31 ulp perturbation,
// absorbed by the exact top-2 rescore); slot = 2*stage+subtile recovers cidx.
__global__ __launch_bounds__(256, 4) void vq_mfma_kernel(
    const float* __restrict__ enc, const float* __restrict__ cb,
    const u16* __restrict__ cb_hi, const u16* __restrict__ cb_lo,
    const float* __restrict__ hcsq, u64* __restrict__ winner)
{
    // ldsb: 2 bufs x 16KB = 8192 u32 | hcsq 4KB = 36 KB total (4 blocks/CU).
    // post-loop: keys[128][33] (4224 u32) reuses the front (ldsb dead by then).
    __shared__ __align__(16) u32 smem[8192 + 1024];
    u16*   ldsb  = (u16*)smem;
    float* lds_h = (float*)(smem + 8192);
    u32*   keys  = smem;

    const int tid  = threadIdx.x;
    const int wave = tid >> 6;
    const int lane = tid & 63;
    const int n32  = lane & 31;
    const int lh   = lane >> 5;
    const int B0   = blockIdx.y * SPLIT_K;
    const int rowbase = blockIdx.x * 128 + wave * 32;      // 32 m-rows per wave

    // ---- A fragments (hi/lo per k-chunk), converted in-register once ----
    short8v a_hi[4], a_lo[4];
    const float* arow = enc + (size_t)(rowbase + n32) * D_DIM + lh * 8;
#pragma unroll
    for (int c = 0; c < 4; ++c) {
        const float4 u0 = ((const float4*)(arow + c * 16))[0];
        const float4 u1 = ((const float4*)(arow + c * 16))[1];
        const float vv[8] = {u0.x,u0.y,u0.z,u0.w,u1.x,u1.y,u1.z,u1.w};
        short8v h8, l8;
#pragma unroll
        for (int j = 0; j < 8; ++j) {
            const u16 h = f2bf(vv[j]);
            h8[j] = (short)h;
            l8[j] = (short)f2bf(vv[j] - bf2f(h));
        }
        a_hi[c] = h8; a_lo[c] = l8;
    }

    // ---- split's hcsq into LDS (once) ----
#pragma unroll
    for (int i = 0; i < SPLIT_K / 256; ++i)
        lds_h[tid + i * 256] = hcsq[B0 + tid + i * 256];

    // ---- DMA mapping: wave (half = w>>1) issues c = (w&1)*2 + {0,1}, u = {0,1}
    // granule slot = lane (n=lane&31, octet=2c+(lane>>5)) -> contiguous b128 read.
    const int half  = wave >> 1;
    const int cpair = (wave & 1) * 2;
    const u16* gbase = (half ? cb_lo : cb_hi) + (size_t)B0 * D_DIM;

#define DMA_STAGE(buf_, s_)                                                          \
    do {                                                                             \
        _Pragma("unroll")                                                            \
        for (int u_ = 0; u_ < 2; ++u_) {                                             \
            _Pragma("unroll")                                                        \
            for (int i_ = 0; i_ < 2; ++i_) {                                         \
                const int c_ = cpair + i_;                                           \
                __builtin_amdgcn_global_load_lds(                                    \
                    (const __attribute__((address_space(1))) void*)                  \
                        (gbase + ((size_t)(s_) * STAGE + u_ * 32 + n32) * D_DIM      \
                               + (2 * c_ + lh) * 8),                                 \
                    (__attribute__((address_space(3))) void*)                        \
                        (ldsb + (buf_) * 8192 + half * 4096 + u_ * 2048 + c_ * 512), \
                    16, 0, 0);                                                       \
            }                                                                        \
        }                                                                            \
    } while (0)

    DMA_STAGE(0, 0);
    __syncthreads();                                       // stage 0 resident

    f32x16 z;
#pragma unroll
    for (int r = 0; r < 16; ++r) z[r] = 0.f;               // never written: chain seed

    float bkey[16];
#pragma unroll
    for (int r = 0; r < 16; ++r) bkey[r] = -INFINITY;

    for (int s = 0; s < NSTAGES; ++s) {
        const int buf = s & 1;
        DMA_STAGE(buf ^ 1, (s + 1) & (NSTAGES - 1));       // async prefetch (wrap ok)

#pragma unroll
        for (int u = 0; u < 2; ++u) {                      // two 32-n subtiles
            const u16* bb = ldsb + buf * 8192 + u * 2048;
            short8v bh[4], bl[4];
#pragma unroll
            for (int c = 0; c < 4; ++c) {
                bh[c] = *(const short8v*)(bb + c * 512 + lane * 8);
                bl[c] = *(const short8v*)(bb + 4096 + c * 512 + lane * 8);
            }
            const float h = lds_h[s * STAGE + u * 32 + n32];

            // single 12-deep chain: hi.hi x4, hi.lo x4, lo.hi x4 (lo.lo dropped)
            f32x16 acc;
            acc = __builtin_amdgcn_mfma_f32_32x32x16_bf16(a_hi[0], bh[0], z,   0,0,0);
            acc = __builtin_amdgcn_mfma_f32_32x32x16_bf16(a_hi[1], bh[1], acc, 0,0,0);
            acc = __builtin_amdgcn_mfma_f32_32x32x16_bf16(a_hi[2], bh[2], acc, 0,0,0);
            acc = __builtin_amdgcn_mfma_f32_32x32x16_bf16(a_hi[3], bh[3], acc, 0,0,0);
            acc = __builtin_amdgcn_mfma_f32_32x32x16_bf16(a_hi[0], bl[0], acc, 0,0,0);
            acc = __builtin_amdgcn_mfma_f32_32x32x16_bf16(a_hi[1], bl[1], acc, 0,0,0);
            acc = __builtin_amdgcn_mfma_f32_32x32x16_bf16(a_hi[2], bl[2], acc, 0,0,0);
            acc = __builtin_amdgcn_mfma_f32_32x32x16_bf16(a_hi[3], bl[3], acc, 0,0,0);
            acc = __builtin_amdgcn_mfma_f32_32x32x16_bf16(a_lo[0], bh[0], acc, 0,0,0);
            acc = __builtin_amdgcn_mfma_f32_32x32x16_bf16(a_lo[1], bh[1], acc, 0,0,0);
            acc = __builtin_amdgcn_mfma_f32_32x32x16_bf16(a_lo[2], bh[2], acc, 0,0,0);
            acc = __builtin_amdgcn_mfma_f32_32x32x16_bf16(a_lo[3], bh[3], acc, 0,0,0);

            const u32 slot = (u32)(s * 2 + u);             // 5 bits
#pragma unroll
            for (int r = 0; r < 16; ++r) {
                const float sc = acc[r] - h;
                const u32 kb = (__float_as_uint(sc) & 0xFFFFFFE0u) | slot;
                bkey[r] = fmaxf(bkey[r], __uint_as_float(kb));
            }
        }
        __syncthreads();   // all waves done reading buf; prefetch drained (vmcnt0)
    }
#undef DMA_STAGE

    // ---- per-class winners -> keys[row][cls] in LDS (reuses ldsb region) ----
#pragma unroll
    for (int r = 0; r < 16; ++r) {
        const int m = (r & 3) + 8 * (r >> 2) + 4 * lh;
        keys[(wave * 32 + m) * 33 + n32] = __float_as_uint(bkey[r]);
    }
    __syncthreads();

    // ---- top-2 of 32 classes per row (2 threads/row), exact fp32 rescore ----
    {
        const int lrow  = tid >> 1;
        const int hpart = tid & 1;
        float k1 = -INFINITY, k2 = -INFINITY; int c1i = 0, c2i = 0;
#pragma unroll
        for (int c = 0; c < 16; ++c) {
            const int cls = hpart * 16 + c;
            const float kf = __uint_as_float(keys[lrow * 33 + cls]);
            if (kf > k1)      { k2 = k1; c2i = c1i; k1 = kf; c1i = cls; }
            else if (kf > k2) { k2 = kf; c2i = cls; }
        }
        const float ok1 = __shfl_xor(k1, 1, 64);
        const float ok2 = __shfl_xor(k2, 1, 64);
        const int   oc1 = __shfl_xor(c1i, 1, 64);
        const int   oc2 = __shfl_xor(c2i, 1, 64);
        float m1, m2; int mi1, mi2;
        if (ok1 > k1) { m1 = ok1; mi1 = oc1;
                        m2 = (k1 > ok2) ? k1 : ok2; mi2 = (k1 > ok2) ? c1i : oc2; }
        else          { m1 = k1;  mi1 = c1i;
                        m2 = (ok1 > k2) ? ok1 : k2; mi2 = (ok1 > k2) ? oc1 : c2i; }

        const float ck   = hpart ? m2 : m1;
        const int   ccls = hpart ? mi2 : mi1;
        const int   cidx = B0 + (int)(__float_as_uint(ck) & 31u) * 32 + ccls;
        const int   grow = blockIdx.x * 128 + lrow;

        const float4* cp = (const float4*)(cb  + (size_t)cidx * D_DIM);
        const float4* xp = (const float4*)(enc + (size_t)grow * D_DIM);
        float d = 0.f;
#pragma unroll
        for (int i = 0; i < 16; ++i) {
            const float4 cv = cp[i], xv = xp[i];
            float t;
            t = xv.x - cv.x; d = fmaf(t, t, d);
            t = xv.y - cv.y; d = fmaf(t, t, d);
            t = xv.z - cv.z; d = fmaf(t, t, d);
            t = xv.w - cv.w; d = fmaf(t, t, d);
        }
        // (distbits, idx) packed: u64 min == (min dist, then min idx) = jnp first-min.
        // 0xAAAA... ws poison exceeds any packed value (dist sign bit 0): free sentinel.
        const u64 packed = ((u64)__float_as_uint(d) << 32) | (u32)cidx;
        atomicMin(winner + grow, packed);
    }
}

// ---- kernel 2: gather winning codeword rows ----
__global__ void vq_gather_kernel(const float* __restrict__ cb,
                                 const u64* __restrict__ winner,
                                 float* __restrict__ out)
{
    const int g   = blockIdx.x * 256 + threadIdx.x;    // 262144 threads x 16B
    const int row = g >> 4;
    const int c4  = g & 15;
    const int idx = (int)(winner[row] & 0xFFFFFFFFu);
    ((float4*)(out + (size_t)row * D_DIM))[c4] =
        ((const float4*)(cb + (size_t)idx * D_DIM))[c4];
}

extern "C" void kernel_launch(void* const* d_in, const int* in_sizes, int n_in,
                              void* d_out, int out_size, void* d_ws, size_t ws_size,
                              hipStream_t stream) {
    const float* enc = (const float*)d_in[0];   // 16384 x 64 fp32
    const float* cb  = (const float*)d_in[1];   // 8192 x 64 fp32
    float* out = (float*)d_out;

    // ws layout (~2.16 MB): cb_hi | cb_lo | hcsq | winner
    u16* cb_hi  = (u16*)d_ws;                       // 1 MB
    u16* cb_lo  = cb_hi + K_CB * D_DIM;             // 1 MB
    float* hcsq = (float*)(cb_lo + K_CB * D_DIM);   // 32 KB
    u64* winner = (u64*)(hcsq + K_CB);              // 128 KB (8-byte aligned)

    vq_prep_kernel<<<K_CB / 8, 256, 0, stream>>>(cb, cb_hi, cb_lo, hcsq);

    dim3 g1(N_ROWS / 128, NSPLIT);                  // 128 x 8 = 1024 blocks
    vq_mfma_kernel<<<g1, 256, 0, stream>>>(enc, cb, cb_hi, cb_lo, hcsq, winner);

    vq_gather_kernel<<<(N_ROWS * 16) / 256, 256, 0, stream>>>(cb, winner, out);
}

// Round 11
// 123.559 us; speedup vs baseline: 1.2487x; 1.0130x over previous
//
#include <hip/hip_runtime.h>

#define N_ROWS 16384
#define K_CB   8192
#define D_DIM  64
#define NSPLIT 8
#define SPLIT_K (K_CB / NSPLIT)          // 1024
#define STAGE  64                        // codebook rows per LDS stage (two 32-n tiles)
#define NSTAGES (SPLIT_K / STAGE)        // 16  -> slot = 2*s+u in [0,32): 5 bits
#define BLKT   128                       // 2 waves per block

typedef unsigned short u16;
typedef unsigned int   u32;
typedef unsigned long long u64;
typedef __attribute__((ext_vector_type(8)))  short short8v;  // 8 bf16 (4 VGPRs)
typedef __attribute__((ext_vector_type(16))) float f32x16;   // 32x32 MFMA C/D

static __device__ __forceinline__ u16 f2bf(float f) {        // RNE fp32->bf16
    unsigned u = __float_as_uint(f);
    return (u16)((u + 0x7FFFu + ((u >> 16) & 1u)) >> 16);
}
static __device__ __forceinline__ float bf2f(u16 h) {
    return __uint_as_float(((unsigned)h) << 16);
}

// ---- kernel 0: codebook prep. hi/lo split + 0.5*||c||^2. 8 rows/block. ----
__global__ void vq_prep_kernel(const float* __restrict__ cb,
                               u16* __restrict__ cb_hi, u16* __restrict__ cb_lo,
                               float* __restrict__ hcsq)
{
    const int wave = threadIdx.x >> 6;
    const int lane = threadIdx.x & 63;
#pragma unroll
    for (int rr = 0; rr < 2; ++rr) {
        const int r = blockIdx.x * 8 + wave * 2 + rr;
        const float v = cb[r * D_DIM + lane];
        const u16 h = f2bf(v);
        cb_hi[r * D_DIM + lane] = h;
        cb_lo[r * D_DIM + lane] = f2bf(v - bf2f(h));
        float d = v * v;
#pragma unroll
        for (int m = 1; m < 64; m <<= 1) d += __shfl_xor(d, m, 64);
        if (lane == 0) hcsq[r] = 0.5f * d;
    }
}

// ---- kernel 1: 32x32x16 MFMA scores, 2 m-tiles/wave (64 rows), float-key
//      argmax + exact fp32 top-2 rescore ----
// score(m,n) = dot(x_m, c_n) - 0.5||c_n||^2 ; argmin dist == argmax score.
// A operand: m=lane&31, k=(lane>>5)*8+j. B operand: n=lane&31, k=(lane>>5)*8+j.
// C/D: col(n)=lane&31, row(m)=(reg&3)+8*(reg>>2)+4*(lane>>5)   [m74/m101].
// Key: bits(score) & ~31 | slot, kept with v_max_f32 (<=31 ulp perturbation,
// absorbed by exact top-2 rescore); slot = 2*stage+subtile recovers cidx.
__global__ __launch_bounds__(BLKT, 2) void vq_mfma_kernel(
    const float* __restrict__ enc, const float* __restrict__ cb,
    const u16* __restrict__ cb_hi, const u16* __restrict__ cb_lo,
    const float* __restrict__ hcsq, u64* __restrict__ winner)
{
    // ldsb: 2 bufs x 16KB = 8192 u32 | hcsq 4KB = 36 KB total (4 blocks/CU).
    // post-loop: keys[128][33] (4224 u32) reuses the front (ldsb dead by then).
    __shared__ __align__(16) u32 smem[8192 + 1024];
    u16*   ldsb  = (u16*)smem;
    float* lds_h = (float*)(smem + 8192);
    u32*   keys  = smem;

    const int tid  = threadIdx.x;
    const int wave = tid >> 6;                             // 0..1
    const int lane = tid & 63;
    const int n32  = lane & 31;
    const int lh   = lane >> 5;
    const int B0   = blockIdx.y * SPLIT_K;
    const int rowbase = blockIdx.x * 128 + wave * 64;      // 64 m-rows per wave

    // ---- A fragments: 2 m-tiles x (hi/lo) x 4 k-chunks, converted once ----
    short8v a_hi[2][4], a_lo[2][4];
#pragma unroll
    for (int mt = 0; mt < 2; ++mt) {
        const float* arow = enc + (size_t)(rowbase + mt * 32 + n32) * D_DIM + lh * 8;
#pragma unroll
        for (int c = 0; c < 4; ++c) {
            const float4 u0 = ((const float4*)(arow + c * 16))[0];
            const float4 u1 = ((const float4*)(arow + c * 16))[1];
            const float vv[8] = {u0.x,u0.y,u0.z,u0.w,u1.x,u1.y,u1.z,u1.w};
            short8v h8, l8;
#pragma unroll
            for (int j = 0; j < 8; ++j) {
                const u16 h = f2bf(vv[j]);
                h8[j] = (short)h;
                l8[j] = (short)f2bf(vv[j] - bf2f(h));
            }
            a_hi[mt][c] = h8; a_lo[mt][c] = l8;
        }
    }

    // ---- split's hcsq into LDS (once) ----
#pragma unroll
    for (int i = 0; i < SPLIT_K / BLKT; ++i)
        lds_h[tid + i * BLKT] = hcsq[B0 + tid + i * BLKT];

    // ---- DMA: wave = half (hi/lo); each thread issues u(2) x c(4) loads ----
    // granule slot = lane (n=lane&31, octet=2c+lh) -> contiguous b128 read.
    const int half = wave;
    const u16* gbase = (half ? cb_lo : cb_hi) + (size_t)B0 * D_DIM;

#define DMA_STAGE(buf_, s_)                                                          \
    do {                                                                             \
        _Pragma("unroll")                                                            \
        for (int u_ = 0; u_ < 2; ++u_) {                                             \
            _Pragma("unroll")                                                        \
            for (int c_ = 0; c_ < 4; ++c_) {                                         \
                __builtin_amdgcn_global_load_lds(                                    \
                    (const __attribute__((address_space(1))) void*)                  \
                        (gbase + ((size_t)(s_) * STAGE + u_ * 32 + n32) * D_DIM      \
                               + (2 * c_ + lh) * 8),                                 \
                    (__attribute__((address_space(3))) void*)                        \
                        (ldsb + (buf_) * 8192 + half * 4096 + u_ * 2048 + c_ * 512), \
                    16, 0, 0);                                                       \
            }                                                                        \
        }                                                                            \
    } while (0)

    DMA_STAGE(0, 0);
    __syncthreads();                                       // stage 0 resident

    f32x16 z;
#pragma unroll
    for (int r = 0; r < 16; ++r) z[r] = 0.f;               // never written: chain seed

    float bkey[2][16];
#pragma unroll
    for (int mt = 0; mt < 2; ++mt)
#pragma unroll
        for (int r = 0; r < 16; ++r) bkey[mt][r] = -INFINITY;

    for (int s = 0; s < NSTAGES; ++s) {
        const int buf = s & 1;
        DMA_STAGE(buf ^ 1, (s + 1) & (NSTAGES - 1));       // async prefetch (wrap ok)

#pragma unroll
        for (int u = 0; u < 2; ++u) {                      // two 32-n subtiles
            const u16* bb = ldsb + buf * 8192 + u * 2048;
            short8v bh[4], bl[4];
#pragma unroll
            for (int c = 0; c < 4; ++c) {
                bh[c] = *(const short8v*)(bb + c * 512 + lane * 8);
                bl[c] = *(const short8v*)(bb + 4096 + c * 512 + lane * 8);
            }
            const float h = lds_h[s * STAGE + u * 32 + n32];
            const u32 slot = (u32)(s * 2 + u);             // 5 bits

#pragma unroll
            for (int mt = 0; mt < 2; ++mt) {               // independent 12-chains
                f32x16 acc;
                acc = __builtin_amdgcn_mfma_f32_32x32x16_bf16(a_hi[mt][0], bh[0], z,   0,0,0);
                acc = __builtin_amdgcn_mfma_f32_32x32x16_bf16(a_hi[mt][1], bh[1], acc, 0,0,0);
                acc = __builtin_amdgcn_mfma_f32_32x32x16_bf16(a_hi[mt][2], bh[2], acc, 0,0,0);
                acc = __builtin_amdgcn_mfma_f32_32x32x16_bf16(a_hi[mt][3], bh[3], acc, 0,0,0);
                acc = __builtin_amdgcn_mfma_f32_32x32x16_bf16(a_hi[mt][0], bl[0], acc, 0,0,0);
                acc = __builtin_amdgcn_mfma_f32_32x32x16_bf16(a_hi[mt][1], bl[1], acc, 0,0,0);
                acc = __builtin_amdgcn_mfma_f32_32x32x16_bf16(a_hi[mt][2], bl[2], acc, 0,0,0);
                acc = __builtin_amdgcn_mfma_f32_32x32x16_bf16(a_hi[mt][3], bl[3], acc, 0,0,0);
                acc = __builtin_amdgcn_mfma_f32_32x32x16_bf16(a_lo[mt][0], bh[0], acc, 0,0,0);
                acc = __builtin_amdgcn_mfma_f32_32x32x16_bf16(a_lo[mt][1], bh[1], acc, 0,0,0);
                acc = __builtin_amdgcn_mfma_f32_32x32x16_bf16(a_lo[mt][2], bh[2], acc, 0,0,0);
                acc = __builtin_amdgcn_mfma_f32_32x32x16_bf16(a_lo[mt][3], bh[3], acc, 0,0,0);

#pragma unroll
                for (int r = 0; r < 16; ++r) {
                    const float sc = acc[r] - h;
                    const u32 kb = (__float_as_uint(sc) & 0xFFFFFFE0u) | slot;
                    bkey[mt][r] = fmaxf(bkey[mt][r], __uint_as_float(kb));
                }
            }
        }
        __syncthreads();   // all waves done reading buf; prefetch drained (vmcnt0)
    }
#undef DMA_STAGE

    // ---- per-class winners -> keys[row][cls] in LDS (reuses ldsb region) ----
#pragma unroll
    for (int mt = 0; mt < 2; ++mt)
#pragma unroll
        for (int r = 0; r < 16; ++r) {
            const int m = (r & 3) + 8 * (r >> 2) + 4 * lh;
            keys[(wave * 64 + mt * 32 + m) * 33 + n32] = __float_as_uint(bkey[mt][r]);
        }
    __syncthreads();

    // ---- top-2 of 32 classes (1 thread per row), exact fp32 rescore both ----
    {
        float k1 = -INFINITY, k2 = -INFINITY; int c1i = 0, c2i = 0;
#pragma unroll
        for (int cls = 0; cls < 32; ++cls) {
            const float kf = __uint_as_float(keys[tid * 33 + cls]);
            if (kf > k1)      { k2 = k1; c2i = c1i; k1 = kf; c1i = cls; }
            else if (kf > k2) { k2 = kf; c2i = cls; }
        }
        const int idx1 = B0 + (int)(__float_as_uint(k1) & 31u) * 32 + c1i;
        const int idx2 = B0 + (int)(__float_as_uint(k2) & 31u) * 32 + c2i;
        const int grow = blockIdx.x * 128 + tid;

        const float4* xp  = (const float4*)(enc + (size_t)grow * D_DIM);
        const float4* cp1 = (const float4*)(cb  + (size_t)idx1 * D_DIM);
        const float4* cp2 = (const float4*)(cb  + (size_t)idx2 * D_DIM);
        float d1 = 0.f, d2 = 0.f;
#pragma unroll
        for (int i = 0; i < 16; ++i) {
            const float4 xv = xp[i], v1 = cp1[i], v2 = cp2[i];
            float t;
            t = xv.x - v1.x; d1 = fmaf(t, t, d1);
            t = xv.y - v1.y; d1 = fmaf(t, t, d1);
            t = xv.z - v1.z; d1 = fmaf(t, t, d1);
            t = xv.w - v1.w; d1 = fmaf(t, t, d1);
            t = xv.x - v2.x; d2 = fmaf(t, t, d2);
            t = xv.y - v2.y; d2 = fmaf(t, t, d2);
            t = xv.z - v2.z; d2 = fmaf(t, t, d2);
            t = xv.w - v2.w; d2 = fmaf(t, t, d2);
        }
        // (distbits, idx) packed: u64 min == (min dist, then min idx) = jnp first-min.
        // 0xAAAA... ws poison exceeds any packed value (dist sign bit 0): free sentinel.
        atomicMin(winner + grow, ((u64)__float_as_uint(d1) << 32) | (u32)idx1);
        atomicMin(winner + grow, ((u64)__float_as_uint(d2) << 32) | (u32)idx2);
    }
}

// ---- kernel 2: gather winning codeword rows ----
__global__ void vq_gather_kernel(const float* __restrict__ cb,
                                 const u64* __restrict__ winner,
                                 float* __restrict__ out)
{
    const int g   = blockIdx.x * 256 + threadIdx.x;    // 262144 threads x 16B
    const int row = g >> 4;
    const int c4  = g & 15;
    const int idx = (int)(winner[row] & 0xFFFFFFFFu);
    ((float4*)(out + (size_t)row * D_DIM))[c4] =
        ((const float4*)(cb + (size_t)idx * D_DIM))[c4];
}

extern "C" void kernel_launch(void* const* d_in, const int* in_sizes, int n_in,
                              void* d_out, int out_size, void* d_ws, size_t ws_size,
                              hipStream_t stream) {
    const float* enc = (const float*)d_in[0];   // 16384 x 64 fp32
    const float* cb  = (const float*)d_in[1];   // 8192 x 64 fp32
    float* out = (float*)d_out;

    // ws layout (~2.16 MB): cb_hi | cb_lo | hcsq | winner
    u16* cb_hi  = (u16*)d_ws;                       // 1 MB
    u16* cb_lo  = cb_hi + K_CB * D_DIM;             // 1 MB
    float* hcsq = (float*)(cb_lo + K_CB * D_DIM);   // 32 KB
    u64* winner = (u64*)(hcsq + K_CB);              // 128 KB (8-byte aligned)

    vq_prep_kernel<<<K_CB / 8, 256, 0, stream>>>(cb, cb_hi, cb_lo, hcsq);

    dim3 g1(N_ROWS / 128, NSPLIT);                  // 128 x 8 = 1024 blocks of 128 thr
    vq_mfma_kernel<<<g1, BLKT, 0, stream>>>(enc, cb, cb_hi, cb_lo, hcsq, winner);

    vq_gather_kernel<<<(N_ROWS * 16) / 256, 256, 0, stream>>>(cb, winner, out);
}